// Round 5
// baseline (314.397 us; speedup 1.0000x reference)
//
#include <hip/hip_runtime.h>
#include <math.h>

#define NRES 512
#define HH 12
#define PQn 4
#define PVn 8
#define En 16
#define Cn 128
#define Sn 384
#define ATT_COLS 2112   // 192 att_single | 1536 att_pair | 288 points | 96 norms

// workspace float offsets
#define OFF_Q    0
#define OFF_K    (OFF_Q   + HH*NRES*En)
#define OFF_V    (OFF_K   + HH*NRES*En)
#define OFF_LQP  (OFF_V   + HH*NRES*En)
#define OFF_LKP  (OFF_LQP + HH*NRES*12)
#define OFF_LVP  (OFF_LKP + HH*NRES*12)
#define OFF_CS   (OFF_LVP + HH*NRES*24)     // colsum [H][N]
#define OFF_ATT  (OFF_CS  + NRES*HH)        // att [NRES][ATT_COLS]
#define OFF_LG   (OFF_ATT + NRES*ATT_COLS)  // logits/weights [H][N][N] (12.6 MB)
// out-GEMM partial buffer aliases LG (lg dead by then; both 3,145,728 floats)
#define OFF_PART OFF_LG
#define KSPLIT 16
#define KCHUNK (ATT_COLS/KSPLIT)   // 132
#define OROWS 8                    // rows per out-GEMM block

// ---------------------------------------------------------------------------
// Kernel A: projections q/k/v and point projections with frame application.
// ---------------------------------------------------------------------------
__global__ __launch_bounds__(256) void ipa_proj(
    const float* __restrict__ single, const float* __restrict__ Rm,
    const float* __restrict__ tr,
    const float* __restrict__ Wq, const float* __restrict__ Wk,
    const float* __restrict__ Wv, const float* __restrict__ Wqp,
    const float* __restrict__ Wkp, const float* __restrict__ Wvp,
    float* __restrict__ ws)
{
  float* q   = ws + OFF_Q;  float* k   = ws + OFF_K;  float* v   = ws + OFF_V;
  float* lqp = ws + OFF_LQP; float* lkp = ws + OFF_LKP; float* lvp = ws + OFF_LVP;
  const int n0 = blockIdx.x * 8;
  const int g  = blockIdx.y;
  const int tid = threadIdx.x;
  __shared__ float sS[8][388];
  __shared__ float sR[8][9];
  __shared__ float sT[8][3];
  #pragma unroll
  for (int i = 0; i < 3; ++i) {
    int idx = i*256 + tid;
    int r = idx / 96, c4 = idx % 96;
    float4 val = *reinterpret_cast<const float4*>(single + (size_t)(n0 + r)*Sn + c4*4);
    *reinterpret_cast<float4*>(&sS[r][c4*4]) = val;
  }
  if (tid < 72)      sR[tid/9][tid%9] = Rm[(size_t)(n0 + tid/9)*9 + tid%9];
  else if (tid < 96) { int r = (tid-72)/3; sT[r][(tid-72)%3] = tr[(size_t)(n0+r)*3 + (tid-72)%3]; }
  __syncthreads();
  #pragma unroll
  for (int i = 0; i < 3; ++i) {
    int item = i*256 + tid;
    int nl = item & 7;
    int ul = item >> 3;
    int u  = g*96 + ul;
    const float* srow = sS[nl];
    if (u < 576) {
      int which = u/192, r = u%192, h = r>>4, e = r&15;
      const float* W = (which==0 ? Wq : which==1 ? Wk : Wv) + (size_t)h*Sn*En + e;
      float acc = 0.f;
      #pragma unroll 8
      for (int d = 0; d < Sn; ++d) acc = fmaf(srow[d], W[(size_t)d*En], acc);
      float* dst = (which==0 ? q : which==1 ? k : v);
      dst[((size_t)h*NRES + (n0+nl))*En + e] = acc;
    } else {
      int u2 = u - 576;
      const float* W; float* dst;
      if (u2 < 48)      { int h=u2>>2,     p=u2&3;      W = Wqp + (size_t)(h*PQn+p)*Sn*3; dst = lqp + ((size_t)h*NRES + (n0+nl))*12 + p*3; }
      else if (u2 < 96) { int h=(u2-48)>>2,p=(u2-48)&3; W = Wkp + (size_t)(h*PQn+p)*Sn*3; dst = lkp + ((size_t)h*NRES + (n0+nl))*12 + p*3; }
      else              { int h=(u2-96)>>3,p=(u2-96)&7; W = Wvp + (size_t)(h*PVn+p)*Sn*3; dst = lvp + ((size_t)h*NRES + (n0+nl))*24 + p*3; }
      float x0=0.f,x1=0.f,x2=0.f;
      #pragma unroll 4
      for (int d = 0; d < Sn; ++d) {
        float sv = srow[d];
        x0 = fmaf(sv, W[d*3+0], x0);
        x1 = fmaf(sv, W[d*3+1], x1);
        x2 = fmaf(sv, W[d*3+2], x2);
      }
      const float* R8 = sR[nl]; const float* T8 = sT[nl];
      dst[0] = R8[0]*x0 + R8[1]*x1 + R8[2]*x2 + T8[0];
      dst[1] = R8[3]*x0 + R8[4]*x1 + R8[5]*x2 + T8[1];
      dst[2] = R8[6]*x0 + R8[7]*x1 + R8[8]*x2 + T8[2];
    }
  }
}

// ---------------------------------------------------------------------------
// Kernel B: logits[h][n][m] = pair-bias + qk + frame.  Streaming, no LDS.
// grid (512 n, 8 m-tiles of 64), 256 thr. Wave: 16 rows x 4 lanes (r,cq).
// Lane reads pair chunk c4=jg*4+cq -> 16 full 64B segments per load inst.
// 12 head-accumulators in registers; 2-step shfl_xor butterfly over cq;
// lane cq finishes heads 3cq..3cq+2 (qk + frame + softplus).
// ---------------------------------------------------------------------------
__global__ __launch_bounds__(256) void ipa_logits(
    const float* __restrict__ pair, const float* __restrict__ Wb,
    const float* __restrict__ scale_head, float* __restrict__ ws)
{
  const float* q   = ws + OFF_Q;  const float* k   = ws + OFF_K;
  const float* lqp = ws + OFF_LQP; const float* lkp = ws + OFF_LKP;
  float* lg = ws + OFF_LG;
  const int n    = blockIdx.x;
  const int lane = threadIdx.x & 63;
  const int wave = threadIdx.x >> 6;
  const int r    = lane >> 2;          // 0..15
  const int cq   = lane & 3;           // 0..3
  const int m    = blockIdx.y*64 + wave*16 + r;

  const float* prow = pair + ((size_t)n*NRES + m)*Cn;
  float acc[HH];
  #pragma unroll
  for (int h = 0; h < HH; ++h) acc[h] = 0.f;

  #pragma unroll
  for (int jg = 0; jg < 8; ++jg) {
    const int c4 = jg*4 + cq;
    float4 pv = *reinterpret_cast<const float4*>(prow + c4*4);
    const float* wbb = Wb + c4*4;
    #pragma unroll
    for (int h = 0; h < HH; ++h) {
      float4 wb = *reinterpret_cast<const float4*>(wbb + h*Cn);
      acc[h] = fmaf(pv.x, wb.x, acc[h]);
      acc[h] = fmaf(pv.y, wb.y, acc[h]);
      acc[h] = fmaf(pv.z, wb.z, acc[h]);
      acc[h] = fmaf(pv.w, wb.w, acc[h]);
    }
  }
  // reduce over the 4 cq lanes (butterfly) -> all lanes hold full sums
  #pragma unroll
  for (int h = 0; h < HH; ++h) {
    acc[h] += __shfl_xor(acc[h], 1);
    acc[h] += __shfl_xor(acc[h], 2);
  }
  // static selection of this lane's 3 heads (no runtime-indexed array)
  float a0, a1, a2;
  if      (cq == 0) { a0 = acc[0]; a1 = acc[1];  a2 = acc[2];  }
  else if (cq == 1) { a0 = acc[3]; a1 = acc[4];  a2 = acc[5];  }
  else if (cq == 2) { a0 = acc[6]; a1 = acc[7];  a2 = acc[8];  }
  else              { a0 = acc[9]; a1 = acc[10]; a2 = acc[11]; }
  float pb[3] = {a0, a1, a2};

  #pragma unroll
  for (int i = 0; i < 3; ++i) {
    const int h = 3*cq + i;
    const float* qh = q + ((size_t)h*NRES + n)*En;
    const float* kh = k + ((size_t)h*NRES + m)*En;
    float qk = 0.f;
    #pragma unroll
    for (int e = 0; e < En; ++e) qk = fmaf(qh[e], kh[e], qk);
    const float* lq = lqp + ((size_t)h*NRES + n)*12;
    const float* lk = lkp + ((size_t)h*NRES + m)*12;
    float cross = 0.f, Bm = 0.f, An = 0.f;
    #pragma unroll
    for (int jj = 0; jj < 12; ++jj) {
      float a = lq[jj], b = lk[jj];
      cross = fmaf(a, b, cross); Bm = fmaf(b, b, Bm); An = fmaf(a, a, An);
    }
    float gamma = 0.11785113019775793f * __logf(1.f + __expf(scale_head[h]));
    lg[((size_t)h*NRES + n)*NRES + m] = pb[i] + 0.25f*qk - gamma*(An + Bm - 2.f*cross);
  }
}

// ---------------------------------------------------------------------------
// Kernel C: softmax in place over last axis of lg[H][N][N]. One wave per row.
// ---------------------------------------------------------------------------
__global__ __launch_bounds__(256) void ipa_softmax(float* __restrict__ ws)
{
  float* lg = ws + OFF_LG;
  const int row  = blockIdx.x*4 + (threadIdx.x >> 6);
  const int lane = threadIdx.x & 63;
  float4* p = reinterpret_cast<float4*>(lg + (size_t)row*NRES);
  float4 x0 = p[lane];
  float4 x1 = p[64 + lane];
  float mx = fmaxf(fmaxf(fmaxf(x0.x,x0.y),fmaxf(x0.z,x0.w)),
                   fmaxf(fmaxf(x1.x,x1.y),fmaxf(x1.z,x1.w)));
  #pragma unroll
  for (int off = 32; off >= 1; off >>= 1) mx = fmaxf(mx, __shfl_xor(mx, off));
  x0.x = __expf(x0.x-mx); x0.y = __expf(x0.y-mx); x0.z = __expf(x0.z-mx); x0.w = __expf(x0.w-mx);
  x1.x = __expf(x1.x-mx); x1.y = __expf(x1.y-mx); x1.z = __expf(x1.z-mx); x1.w = __expf(x1.w-mx);
  float sum = x0.x+x0.y+x0.z+x0.w + x1.x+x1.y+x1.z+x1.w;
  #pragma unroll
  for (int off = 32; off >= 1; off >>= 1) sum += __shfl_xor(sum, off);
  const float inv = 1.f/sum;
  x0.x*=inv; x0.y*=inv; x0.z*=inv; x0.w*=inv;
  x1.x*=inv; x1.y*=inv; x1.z*=inv; x1.w*=inv;
  p[lane] = x0;
  p[64 + lane] = x1;
}

// ---------------------------------------------------------------------------
// Kernel D: colsum[h][b] = sum_a w[h][a][b]. grid (12, 8 a-chunks).
// ---------------------------------------------------------------------------
__global__ __launch_bounds__(256) void ipa_colsum(float* __restrict__ ws)
{
  const float* lg = ws + OFF_LG;
  float* cs = ws + OFF_CS;
  const int h = blockIdx.x, ac = blockIdx.y, tid = threadIdx.x;
  const float* base = lg + (size_t)h*NRES*NRES + (size_t)ac*64*NRES;
  float acc0 = 0.f, acc1 = 0.f;
  #pragma unroll 4
  for (int a = 0; a < 64; ++a) {
    acc0 += base[(size_t)a*NRES + tid];
    acc1 += base[(size_t)a*NRES + tid + 256];
  }
  atomicAdd(&cs[h*NRES + tid],       acc0);
  atomicAdd(&cs[h*NRES + tid + 256], acc1);
}

// ---------------------------------------------------------------------------
// Kernel E: att_single = w.v, local_out = w.lvp, inverse frame + norms.
// ---------------------------------------------------------------------------
__global__ __launch_bounds__(256) void ipa_agg(
    const float* __restrict__ Rm, const float* __restrict__ tr,
    float* __restrict__ ws)
{
  const float* v   = ws + OFF_V;
  const float* lvp = ws + OFF_LVP;
  const float* lg  = ws + OFF_LG;
  float* att = ws + OFF_ATT;
  const int row  = blockIdx.x*4 + (threadIdx.x >> 6);
  const int lane = threadIdx.x & 63;
  const int h = row >> 9, n = row & 511;

  float acc[40];
  #pragma unroll
  for (int i = 0; i < 40; ++i) acc[i] = 0.f;

  const float* wrow = lg + (size_t)row*NRES;
  #pragma unroll 2
  for (int j = 0; j < 8; ++j) {
    const int m = j*64 + lane;
    const float wv = wrow[m];
    const float4* v4 = reinterpret_cast<const float4*>(v + ((size_t)h*NRES + m)*En);
    float4 a0=v4[0], a1=v4[1], a2=v4[2], a3=v4[3];
    acc[0]+=wv*a0.x; acc[1]+=wv*a0.y; acc[2]+=wv*a0.z; acc[3]+=wv*a0.w;
    acc[4]+=wv*a1.x; acc[5]+=wv*a1.y; acc[6]+=wv*a1.z; acc[7]+=wv*a1.w;
    acc[8]+=wv*a2.x; acc[9]+=wv*a2.y; acc[10]+=wv*a2.z; acc[11]+=wv*a2.w;
    acc[12]+=wv*a3.x; acc[13]+=wv*a3.y; acc[14]+=wv*a3.z; acc[15]+=wv*a3.w;
    const float4* l4 = reinterpret_cast<const float4*>(lvp + ((size_t)h*NRES + m)*24);
    #pragma unroll
    for (int t = 0; t < 6; ++t) {
      float4 b = l4[t];
      acc[16+4*t+0]+=wv*b.x; acc[16+4*t+1]+=wv*b.y;
      acc[16+4*t+2]+=wv*b.z; acc[16+4*t+3]+=wv*b.w;
    }
  }
  #pragma unroll
  for (int off = 32; off >= 1; off >>= 1) {
    #pragma unroll
    for (int i = 0; i < 40; ++i) acc[i] += __shfl_xor(acc[i], off);
  }
  if (lane == 0) {
    size_t ab = (size_t)n*ATT_COLS;
    float4* as = reinterpret_cast<float4*>(att + ab + h*En);
    as[0] = make_float4(acc[0],acc[1],acc[2],acc[3]);
    as[1] = make_float4(acc[4],acc[5],acc[6],acc[7]);
    as[2] = make_float4(acc[8],acc[9],acc[10],acc[11]);
    as[3] = make_float4(acc[12],acc[13],acc[14],acc[15]);
    const float R0=Rm[n*9+0],R1=Rm[n*9+1],R2=Rm[n*9+2],
                R3=Rm[n*9+3],R4=Rm[n*9+4],R5=Rm[n*9+5],
                R6=Rm[n*9+6],R7=Rm[n*9+7],R8=Rm[n*9+8];
    const float t0=tr[n*3+0], t1=tr[n*3+1], t2=tr[n*3+2];
    #pragma unroll
    for (int pp = 0; pp < 8; ++pp) {
      float d0 = acc[16+3*pp+0]-t0, d1 = acc[16+3*pp+1]-t1, d2 = acc[16+3*pp+2]-t2;
      float g0 = R0*d0 + R3*d1 + R6*d2;
      float g1 = R1*d0 + R4*d1 + R7*d2;
      float g2 = R2*d0 + R5*d1 + R8*d2;
      att[ab + 1728 + (pp*HH + h)*3 + 0] = g0;
      att[ab + 1728 + (pp*HH + h)*3 + 1] = g1;
      att[ab + 1728 + (pp*HH + h)*3 + 2] = g2;
      att[ab + 2016 + pp*HH + h] = sqrtf(g0*g0 + g1*g1 + g2*g2);
    }
  }
}

// ---------------------------------------------------------------------------
// Kernel F: att_pair[h,i,c] = sum_b colsum[h,b]*pair[i,b,c]. One block per i.
// ---------------------------------------------------------------------------
__global__ __launch_bounds__(256) void ipa_pairagg(
    const float* __restrict__ pair, float* __restrict__ ws)
{
  const float* cs = ws + OFF_CS;
  float* att = ws + OFF_ATT;
  const int i = blockIdx.x, tid = threadIdx.x;
  __shared__ float sCS[HH*NRES];
  __shared__ float4 sRed[8][HH][32];
  #pragma unroll
  for (int it = 0; it < 6; ++it) {
    int idx = it*256 + tid;
    reinterpret_cast<float4*>(sCS)[idx] = reinterpret_cast<const float4*>(cs)[idx];
  }
  __syncthreads();
  const int c4 = tid & 31, bg = tid >> 5;
  float4 acc[HH];
  #pragma unroll
  for (int h = 0; h < HH; ++h) acc[h] = make_float4(0.f,0.f,0.f,0.f);
  const float* prow = pair + (size_t)i*NRES*Cn;
  for (int b = bg; b < NRES; b += 8) {
    float4 pv = *reinterpret_cast<const float4*>(prow + (size_t)b*Cn + c4*4);
    #pragma unroll
    for (int h = 0; h < HH; ++h) {
      float w = sCS[h*NRES + b];
      acc[h].x = fmaf(w, pv.x, acc[h].x);
      acc[h].y = fmaf(w, pv.y, acc[h].y);
      acc[h].z = fmaf(w, pv.z, acc[h].z);
      acc[h].w = fmaf(w, pv.w, acc[h].w);
    }
  }
  #pragma unroll
  for (int h = 0; h < HH; ++h) sRed[bg][h][c4] = acc[h];
  __syncthreads();
  for (int s = 4; s >= 1; s >>= 1) {
    if (bg < s) {
      #pragma unroll
      for (int h = 0; h < HH; ++h) {
        float4 a = sRed[bg][h][c4], b2 = sRed[bg+s][h][c4];
        a.x+=b2.x; a.y+=b2.y; a.z+=b2.z; a.w+=b2.w;
        sRed[bg][h][c4] = a;
      }
    }
    __syncthreads();
  }
  if (bg == 0) {
    size_t base = (size_t)i*ATT_COLS + 192;
    #pragma unroll
    for (int h = 0; h < HH; ++h)
      *reinterpret_cast<float4*>(att + base + h*Cn + c4*4) = sRed[0][h][c4];
  }
}

// ---------------------------------------------------------------------------
// Kernel G1: split-k partial GEMM. grid (64 rowblocks, 16 ksplits), 384 thr.
// ---------------------------------------------------------------------------
__global__ __launch_bounds__(384) void ipa_outp(
    const float* __restrict__ att, const float* __restrict__ Wout,
    float* __restrict__ ws)
{
  float* partial = ws + OFF_PART;       // [KSPLIT][NRES][Sn]
  const int rb = blockIdx.x;
  const int ks = blockIdx.y;
  const int s  = threadIdx.x;
  const int n0 = rb*OROWS;
  const int j0 = ks*KCHUNK;

  float acc[OROWS];
  #pragma unroll
  for (int r = 0; r < OROWS; ++r) acc[r] = 0.f;

  for (int jg = 0; jg < KCHUNK/4; ++jg) {
    const int j = j0 + jg*4;
    float w0 = Wout[(size_t)(j+0)*Sn + s];
    float w1 = Wout[(size_t)(j+1)*Sn + s];
    float w2 = Wout[(size_t)(j+2)*Sn + s];
    float w3 = Wout[(size_t)(j+3)*Sn + s];
    #pragma unroll
    for (int r = 0; r < OROWS; ++r) {
      float4 av = *reinterpret_cast<const float4*>(att + (size_t)(n0+r)*ATT_COLS + j);
      acc[r] = fmaf(av.x, w0, acc[r]);
      acc[r] = fmaf(av.y, w1, acc[r]);
      acc[r] = fmaf(av.z, w2, acc[r]);
      acc[r] = fmaf(av.w, w3, acc[r]);
    }
  }
  #pragma unroll
  for (int r = 0; r < OROWS; ++r)
    partial[((size_t)ks*NRES + n0 + r)*Sn + s] = acc[r];
}

// ---------------------------------------------------------------------------
// Kernel G2: out[n][s] = b_out[s] + sum_ks partial[ks][n][s].
// ---------------------------------------------------------------------------
__global__ __launch_bounds__(384) void ipa_outred(
    const float* __restrict__ b_out, float* __restrict__ ws,
    float* __restrict__ out)
{
  const float* partial = ws + OFF_PART;
  const int n = blockIdx.x, s = threadIdx.x;
  float a = b_out[s];
  #pragma unroll
  for (int ks = 0; ks < KSPLIT; ++ks)
    a += partial[((size_t)ks*NRES + n)*Sn + s];
  out[(size_t)n*Sn + s] = a;
}

// ---------------------------------------------------------------------------
extern "C" void kernel_launch(void* const* d_in, const int* in_sizes, int n_in,
                              void* d_out, int out_size, void* d_ws, size_t ws_size,
                              hipStream_t stream) {
  const float* single = (const float*)d_in[0];
  const float* pair   = (const float*)d_in[1];
  const float* Rm     = (const float*)d_in[2];
  const float* tr     = (const float*)d_in[3];
  const float* Wq     = (const float*)d_in[4];
  const float* Wk     = (const float*)d_in[5];
  const float* Wv     = (const float*)d_in[6];
  const float* Wqp    = (const float*)d_in[7];
  const float* Wkp    = (const float*)d_in[8];
  const float* Wvp    = (const float*)d_in[9];
  const float* Wb     = (const float*)d_in[10];
  const float* Wout   = (const float*)d_in[11];
  const float* b_out  = (const float*)d_in[12];
  const float* scale_head = (const float*)d_in[13];
  float* ws  = (float*)d_ws;
  float* out = (float*)d_out;

  hipMemsetAsync(ws + OFF_CS, 0, NRES*HH*sizeof(float), stream);
  ipa_proj   <<<dim3(64, 8),  256, 0, stream>>>(single, Rm, tr, Wq, Wk, Wv, Wqp, Wkp, Wvp, ws);
  ipa_logits <<<dim3(NRES, 8),256, 0, stream>>>(pair, Wb, scale_head, ws);
  ipa_softmax<<<dim3(HH*NRES/4), 256, 0, stream>>>(ws);
  ipa_colsum <<<dim3(HH, 8),  256, 0, stream>>>(ws);
  ipa_agg    <<<dim3(HH*NRES/4), 256, 0, stream>>>(Rm, tr, ws);
  ipa_pairagg<<<dim3(NRES),   256, 0, stream>>>(pair, ws);
  ipa_outp   <<<dim3(NRES/OROWS, KSPLIT), 384, 0, stream>>>(ws + OFF_ATT, Wout, ws);
  ipa_outred <<<dim3(NRES),   384, 0, stream>>>(b_out, ws, out);
}

// Round 6
// 265.285 us; speedup vs baseline: 1.1851x; 1.1851x over previous
//
#include <hip/hip_runtime.h>
#include <math.h>

#define NRES 512
#define HH 12
#define PQn 4
#define PVn 8
#define En 16
#define Cn 128
#define Sn 384
#define ATT_COLS 2112   // 192 att_single | 1536 att_pair | 288 points | 96 norms

// workspace float offsets
#define OFF_Q    0
#define OFF_K    (OFF_Q   + HH*NRES*En)
#define OFF_V    (OFF_K   + HH*NRES*En)
#define OFF_LQP  (OFF_V   + HH*NRES*En)
#define OFF_LKP  (OFF_LQP + HH*NRES*12)
#define OFF_LVP  (OFF_LKP + HH*NRES*12)
#define OFF_CS   (OFF_LVP + HH*NRES*24)     // colsum [H][N]
#define OFF_ATT  (OFF_CS  + NRES*HH)        // att [NRES][ATT_COLS]
#define OFF_LG   (OFF_ATT + NRES*ATT_COLS)  // logits/weights [H][N][N] (12.6 MB)
// out-GEMM partial buffer aliases LG (lg dead by then)
#define OFF_PART OFF_LG
// packed logit operands alias ATT (att not written until ipa_agg/pairagg,
// which run after ipa_logits has consumed these)
#define OFF_KC   OFF_ATT                    // [N][H][28]
#define OFF_D1   (OFF_KC + NRES*HH*28)      // [N][H]  -gamma*|lkp|^2
#define OFF_D0   (OFF_D1 + NRES*HH)         // [N][H]  -gamma*|lqp|^2
#define KSPLIT 16
#define KCHUNK (ATT_COLS/KSPLIT)   // 132
#define OROWS 8                    // rows per out-GEMM block
#define NGRP 2                     // query rows per logits block

// ---------------------------------------------------------------------------
// Kernel A: projections q/k/v and point projections with frame application.
// ---------------------------------------------------------------------------
__global__ __launch_bounds__(256) void ipa_proj(
    const float* __restrict__ single, const float* __restrict__ Rm,
    const float* __restrict__ tr,
    const float* __restrict__ Wq, const float* __restrict__ Wk,
    const float* __restrict__ Wv, const float* __restrict__ Wqp,
    const float* __restrict__ Wkp, const float* __restrict__ Wvp,
    float* __restrict__ ws)
{
  float* q   = ws + OFF_Q;  float* k   = ws + OFF_K;  float* v   = ws + OFF_V;
  float* lqp = ws + OFF_LQP; float* lkp = ws + OFF_LKP; float* lvp = ws + OFF_LVP;
  const int n0 = blockIdx.x * 8;
  const int g  = blockIdx.y;
  const int tid = threadIdx.x;
  __shared__ float sS[8][388];
  __shared__ float sR[8][9];
  __shared__ float sT[8][3];
  #pragma unroll
  for (int i = 0; i < 3; ++i) {
    int idx = i*256 + tid;
    int r = idx / 96, c4 = idx % 96;
    float4 val = *reinterpret_cast<const float4*>(single + (size_t)(n0 + r)*Sn + c4*4);
    *reinterpret_cast<float4*>(&sS[r][c4*4]) = val;
  }
  if (tid < 72)      sR[tid/9][tid%9] = Rm[(size_t)(n0 + tid/9)*9 + tid%9];
  else if (tid < 96) { int r = (tid-72)/3; sT[r][(tid-72)%3] = tr[(size_t)(n0+r)*3 + (tid-72)%3]; }
  __syncthreads();
  #pragma unroll
  for (int i = 0; i < 3; ++i) {
    int item = i*256 + tid;
    int nl = item & 7;
    int ul = item >> 3;
    int u  = g*96 + ul;
    const float* srow = sS[nl];
    if (u < 576) {
      int which = u/192, r = u%192, h = r>>4, e = r&15;
      const float* W = (which==0 ? Wq : which==1 ? Wk : Wv) + (size_t)h*Sn*En + e;
      float acc = 0.f;
      #pragma unroll 8
      for (int d = 0; d < Sn; ++d) acc = fmaf(srow[d], W[(size_t)d*En], acc);
      float* dst = (which==0 ? q : which==1 ? k : v);
      dst[((size_t)h*NRES + (n0+nl))*En + e] = acc;
    } else {
      int u2 = u - 576;
      const float* W; float* dst;
      if (u2 < 48)      { int h=u2>>2,     p=u2&3;      W = Wqp + (size_t)(h*PQn+p)*Sn*3; dst = lqp + ((size_t)h*NRES + (n0+nl))*12 + p*3; }
      else if (u2 < 96) { int h=(u2-48)>>2,p=(u2-48)&3; W = Wkp + (size_t)(h*PQn+p)*Sn*3; dst = lkp + ((size_t)h*NRES + (n0+nl))*12 + p*3; }
      else              { int h=(u2-96)>>3,p=(u2-96)&7; W = Wvp + (size_t)(h*PVn+p)*Sn*3; dst = lvp + ((size_t)h*NRES + (n0+nl))*24 + p*3; }
      float x0=0.f,x1=0.f,x2=0.f;
      #pragma unroll 4
      for (int d = 0; d < Sn; ++d) {
        float sv = srow[d];
        x0 = fmaf(sv, W[d*3+0], x0);
        x1 = fmaf(sv, W[d*3+1], x1);
        x2 = fmaf(sv, W[d*3+2], x2);
      }
      const float* R8 = sR[nl]; const float* T8 = sT[nl];
      dst[0] = R8[0]*x0 + R8[1]*x1 + R8[2]*x2 + T8[0];
      dst[1] = R8[3]*x0 + R8[4]*x1 + R8[5]*x2 + T8[1];
      dst[2] = R8[6]*x0 + R8[7]*x1 + R8[8]*x2 + T8[2];
    }
  }
}

// ---------------------------------------------------------------------------
// Kernel A2: pack per-(m,h) logit operands.
// kc[m][h][0:16]  = 0.25 * k[h][m][:]
// kc[m][h][16:28] = 2*gamma_h * lkp[h][m][:]
// d1[m][h] = -gamma_h * |lkp[h][m]|^2 ; d0[n][h] = -gamma_h * |lqp[h][n]|^2
// grid 24 x 256 (h = idx>>9, m = idx&511 -> coalesced reads).
// ---------------------------------------------------------------------------
__global__ __launch_bounds__(256) void ipa_pack(
    const float* __restrict__ scale_head, float* __restrict__ ws)
{
  const float* k   = ws + OFF_K;
  const float* lkp = ws + OFF_LKP;
  const float* lqp = ws + OFF_LQP;
  float* kc = ws + OFF_KC;
  float* d1 = ws + OFF_D1;
  float* d0 = ws + OFF_D0;
  const int idx = blockIdx.x*256 + threadIdx.x;   // 0..6143
  const int h = idx >> 9, m = idx & 511;
  const float gamma = 0.11785113019775793f * log1pf(__expf(scale_head[h]));
  const float* kr  = k   + ((size_t)h*NRES + m)*En;
  const float* lkr = lkp + ((size_t)h*NRES + m)*12;
  const float* lqr = lqp + ((size_t)h*NRES + m)*12;
  float* kcr = kc + ((size_t)m*HH + h)*28;
  #pragma unroll
  for (int e = 0; e < En; ++e) kcr[e] = 0.25f * kr[e];
  float Bm = 0.f, An = 0.f;
  #pragma unroll
  for (int j = 0; j < 12; ++j) {
    float b = lkr[j];
    kcr[16+j] = (2.f*gamma)*b;
    Bm = fmaf(b, b, Bm);
    float a = lqr[j];
    An = fmaf(a, a, An);
  }
  d1[m*HH + h] = -gamma*Bm;
  d0[m*HH + h] = -gamma*An;   // read later as d0[n*HH+h]
}

// ---------------------------------------------------------------------------
// Kernel B: logits[h][n][m]. Streaming, no LDS. Each thread owns pair row m
// for NGRP query rows. Wb indexed only by loop counters -> wave-uniform
// s_load. kc row read sequentially (7 float4 per head). q-side uniform.
// grid (NRES/NGRP, NRES/256), 256 thr.
// ---------------------------------------------------------------------------
__global__ __launch_bounds__(256) void ipa_logits(
    const float* __restrict__ pair, const float* __restrict__ Wb,
    float* __restrict__ ws)
{
  const float* q   = ws + OFF_Q;
  const float* lqp = ws + OFF_LQP;
  const float* kc  = ws + OFF_KC;
  const float* d1  = ws + OFF_D1;
  const float* d0  = ws + OFF_D0;
  float* lg = ws + OFF_LG;
  const int n0 = blockIdx.x * NGRP;
  const int m  = blockIdx.y * 256 + threadIdx.x;

  float acc[NGRP][HH];
  #pragma unroll
  for (int g = 0; g < NGRP; ++g)
    #pragma unroll
    for (int h = 0; h < HH; ++h) acc[g][h] = 0.f;

  const float4* prow0 = reinterpret_cast<const float4*>(pair + ((size_t)(n0+0)*NRES + m)*Cn);
  const float4* prow1 = reinterpret_cast<const float4*>(pair + ((size_t)(n0+1)*NRES + m)*Cn);
  #pragma unroll 4
  for (int c4 = 0; c4 < 32; ++c4) {
    float4 p0 = prow0[c4];
    float4 p1 = prow1[c4];
    #pragma unroll
    for (int h = 0; h < HH; ++h) {
      float4 wb = *reinterpret_cast<const float4*>(Wb + h*Cn + c4*4);  // uniform
      acc[0][h] += p0.x*wb.x + p0.y*wb.y + p0.z*wb.z + p0.w*wb.w;
      acc[1][h] += p1.x*wb.x + p1.y*wb.y + p1.z*wb.z + p1.w*wb.w;
    }
  }

  float d1v[HH];
  {
    const float4* dd = reinterpret_cast<const float4*>(d1 + (size_t)m*HH);
    float4 a = dd[0], b = dd[1], c = dd[2];
    d1v[0]=a.x; d1v[1]=a.y; d1v[2]=a.z; d1v[3]=a.w;
    d1v[4]=b.x; d1v[5]=b.y; d1v[6]=b.z; d1v[7]=b.w;
    d1v[8]=c.x; d1v[9]=c.y; d1v[10]=c.z; d1v[11]=c.w;
  }

  const float* kcrow = kc + (size_t)m*HH*28;
  #pragma unroll
  for (int h = 0; h < HH; ++h) {
    const float4* kcr = reinterpret_cast<const float4*>(kcrow + h*28);
    float4 k0=kcr[0], k1=kcr[1], k2=kcr[2], k3=kcr[3], k4=kcr[4], k5=kcr[5], k6=kcr[6];
    #pragma unroll
    for (int g = 0; g < NGRP; ++g) {
      const int n = n0 + g;
      const float* qh  = q   + ((size_t)h*NRES + n)*En;   // uniform
      const float* lqh = lqp + ((size_t)h*NRES + n)*12;   // uniform
      float s = acc[g][h] + d1v[h] + d0[(size_t)n*HH + h];
      s += k0.x*qh[0]  + k0.y*qh[1]  + k0.z*qh[2]  + k0.w*qh[3];
      s += k1.x*qh[4]  + k1.y*qh[5]  + k1.z*qh[6]  + k1.w*qh[7];
      s += k2.x*qh[8]  + k2.y*qh[9]  + k2.z*qh[10] + k2.w*qh[11];
      s += k3.x*qh[12] + k3.y*qh[13] + k3.z*qh[14] + k3.w*qh[15];
      s += k4.x*lqh[0] + k4.y*lqh[1] + k4.z*lqh[2] + k4.w*lqh[3];
      s += k5.x*lqh[4] + k5.y*lqh[5] + k5.z*lqh[6] + k5.w*lqh[7];
      s += k6.x*lqh[8] + k6.y*lqh[9] + k6.z*lqh[10]+ k6.w*lqh[11];
      lg[((size_t)h*NRES + n)*NRES + m] = s;
    }
  }
}

// ---------------------------------------------------------------------------
// Kernel C: softmax in place over last axis of lg[H][N][N]. One wave per row.
// ---------------------------------------------------------------------------
__global__ __launch_bounds__(256) void ipa_softmax(float* __restrict__ ws)
{
  float* lg = ws + OFF_LG;
  const int row  = blockIdx.x*4 + (threadIdx.x >> 6);
  const int lane = threadIdx.x & 63;
  float4* p = reinterpret_cast<float4*>(lg + (size_t)row*NRES);
  float4 x0 = p[lane];
  float4 x1 = p[64 + lane];
  float mx = fmaxf(fmaxf(fmaxf(x0.x,x0.y),fmaxf(x0.z,x0.w)),
                   fmaxf(fmaxf(x1.x,x1.y),fmaxf(x1.z,x1.w)));
  #pragma unroll
  for (int off = 32; off >= 1; off >>= 1) mx = fmaxf(mx, __shfl_xor(mx, off));
  x0.x = __expf(x0.x-mx); x0.y = __expf(x0.y-mx); x0.z = __expf(x0.z-mx); x0.w = __expf(x0.w-mx);
  x1.x = __expf(x1.x-mx); x1.y = __expf(x1.y-mx); x1.z = __expf(x1.z-mx); x1.w = __expf(x1.w-mx);
  float sum = x0.x+x0.y+x0.z+x0.w + x1.x+x1.y+x1.z+x1.w;
  #pragma unroll
  for (int off = 32; off >= 1; off >>= 1) sum += __shfl_xor(sum, off);
  const float inv = 1.f/sum;
  x0.x*=inv; x0.y*=inv; x0.z*=inv; x0.w*=inv;
  x1.x*=inv; x1.y*=inv; x1.z*=inv; x1.w*=inv;
  p[lane] = x0;
  p[64 + lane] = x1;
}

// ---------------------------------------------------------------------------
// Kernel D: colsum[h][b] = sum_a w[h][a][b]. grid (12, 8 a-chunks).
// ---------------------------------------------------------------------------
__global__ __launch_bounds__(256) void ipa_colsum(float* __restrict__ ws)
{
  const float* lg = ws + OFF_LG;
  float* cs = ws + OFF_CS;
  const int h = blockIdx.x, ac = blockIdx.y, tid = threadIdx.x;
  const float* base = lg + (size_t)h*NRES*NRES + (size_t)ac*64*NRES;
  float acc0 = 0.f, acc1 = 0.f;
  #pragma unroll 4
  for (int a = 0; a < 64; ++a) {
    acc0 += base[(size_t)a*NRES + tid];
    acc1 += base[(size_t)a*NRES + tid + 256];
  }
  atomicAdd(&cs[h*NRES + tid],       acc0);
  atomicAdd(&cs[h*NRES + tid + 256], acc1);
}

// ---------------------------------------------------------------------------
// Kernel E: att_single = w.v, local_out = w.lvp, inverse frame + norms.
// ---------------------------------------------------------------------------
__global__ __launch_bounds__(256) void ipa_agg(
    const float* __restrict__ Rm, const float* __restrict__ tr,
    float* __restrict__ ws)
{
  const float* v   = ws + OFF_V;
  const float* lvp = ws + OFF_LVP;
  const float* lg  = ws + OFF_LG;
  float* att = ws + OFF_ATT;
  const int row  = blockIdx.x*4 + (threadIdx.x >> 6);
  const int lane = threadIdx.x & 63;
  const int h = row >> 9, n = row & 511;

  float acc[40];
  #pragma unroll
  for (int i = 0; i < 40; ++i) acc[i] = 0.f;

  const float* wrow = lg + (size_t)row*NRES;
  #pragma unroll 2
  for (int j = 0; j < 8; ++j) {
    const int m = j*64 + lane;
    const float wv = wrow[m];
    const float4* v4 = reinterpret_cast<const float4*>(v + ((size_t)h*NRES + m)*En);
    float4 a0=v4[0], a1=v4[1], a2=v4[2], a3=v4[3];
    acc[0]+=wv*a0.x; acc[1]+=wv*a0.y; acc[2]+=wv*a0.z; acc[3]+=wv*a0.w;
    acc[4]+=wv*a1.x; acc[5]+=wv*a1.y; acc[6]+=wv*a1.z; acc[7]+=wv*a1.w;
    acc[8]+=wv*a2.x; acc[9]+=wv*a2.y; acc[10]+=wv*a2.z; acc[11]+=wv*a2.w;
    acc[12]+=wv*a3.x; acc[13]+=wv*a3.y; acc[14]+=wv*a3.z; acc[15]+=wv*a3.w;
    const float4* l4 = reinterpret_cast<const float4*>(lvp + ((size_t)h*NRES + m)*24);
    #pragma unroll
    for (int t = 0; t < 6; ++t) {
      float4 b = l4[t];
      acc[16+4*t+0]+=wv*b.x; acc[16+4*t+1]+=wv*b.y;
      acc[16+4*t+2]+=wv*b.z; acc[16+4*t+3]+=wv*b.w;
    }
  }
  #pragma unroll
  for (int off = 32; off >= 1; off >>= 1) {
    #pragma unroll
    for (int i = 0; i < 40; ++i) acc[i] += __shfl_xor(acc[i], off);
  }
  if (lane == 0) {
    size_t ab = (size_t)n*ATT_COLS;
    float4* as = reinterpret_cast<float4*>(att + ab + h*En);
    as[0] = make_float4(acc[0],acc[1],acc[2],acc[3]);
    as[1] = make_float4(acc[4],acc[5],acc[6],acc[7]);
    as[2] = make_float4(acc[8],acc[9],acc[10],acc[11]);
    as[3] = make_float4(acc[12],acc[13],acc[14],acc[15]);
    const float R0=Rm[n*9+0],R1=Rm[n*9+1],R2=Rm[n*9+2],
                R3=Rm[n*9+3],R4=Rm[n*9+4],R5=Rm[n*9+5],
                R6=Rm[n*9+6],R7=Rm[n*9+7],R8=Rm[n*9+8];
    const float t0=tr[n*3+0], t1=tr[n*3+1], t2=tr[n*3+2];
    #pragma unroll
    for (int pp = 0; pp < 8; ++pp) {
      float d0 = acc[16+3*pp+0]-t0, d1 = acc[16+3*pp+1]-t1, d2 = acc[16+3*pp+2]-t2;
      float g0 = R0*d0 + R3*d1 + R6*d2;
      float g1 = R1*d0 + R4*d1 + R7*d2;
      float g2 = R2*d0 + R5*d1 + R8*d2;
      att[ab + 1728 + (pp*HH + h)*3 + 0] = g0;
      att[ab + 1728 + (pp*HH + h)*3 + 1] = g1;
      att[ab + 1728 + (pp*HH + h)*3 + 2] = g2;
      att[ab + 2016 + pp*HH + h] = sqrtf(g0*g0 + g1*g1 + g2*g2);
    }
  }
}

// ---------------------------------------------------------------------------
// Kernel F: att_pair[h,i,c] = sum_b colsum[h,b]*pair[i,b,c]. One block per i.
// ---------------------------------------------------------------------------
__global__ __launch_bounds__(256) void ipa_pairagg(
    const float* __restrict__ pair, float* __restrict__ ws)
{
  const float* cs = ws + OFF_CS;
  float* att = ws + OFF_ATT;
  const int i = blockIdx.x, tid = threadIdx.x;
  __shared__ float sCS[HH*NRES];
  __shared__ float4 sRed[8][HH][32];
  #pragma unroll
  for (int it = 0; it < 6; ++it) {
    int idx = it*256 + tid;
    reinterpret_cast<float4*>(sCS)[idx] = reinterpret_cast<const float4*>(cs)[idx];
  }
  __syncthreads();
  const int c4 = tid & 31, bg = tid >> 5;
  float4 acc[HH];
  #pragma unroll
  for (int h = 0; h < HH; ++h) acc[h] = make_float4(0.f,0.f,0.f,0.f);
  const float* prow = pair + (size_t)i*NRES*Cn;
  for (int b = bg; b < NRES; b += 8) {
    float4 pv = *reinterpret_cast<const float4*>(prow + (size_t)b*Cn + c4*4);
    #pragma unroll
    for (int h = 0; h < HH; ++h) {
      float w = sCS[h*NRES + b];
      acc[h].x = fmaf(w, pv.x, acc[h].x);
      acc[h].y = fmaf(w, pv.y, acc[h].y);
      acc[h].z = fmaf(w, pv.z, acc[h].z);
      acc[h].w = fmaf(w, pv.w, acc[h].w);
    }
  }
  #pragma unroll
  for (int h = 0; h < HH; ++h) sRed[bg][h][c4] = acc[h];
  __syncthreads();
  for (int s = 4; s >= 1; s >>= 1) {
    if (bg < s) {
      #pragma unroll
      for (int h = 0; h < HH; ++h) {
        float4 a = sRed[bg][h][c4], b2 = sRed[bg+s][h][c4];
        a.x+=b2.x; a.y+=b2.y; a.z+=b2.z; a.w+=b2.w;
        sRed[bg][h][c4] = a;
      }
    }
    __syncthreads();
  }
  if (bg == 0) {
    size_t base = (size_t)i*ATT_COLS + 192;
    #pragma unroll
    for (int h = 0; h < HH; ++h)
      *reinterpret_cast<float4*>(att + base + h*Cn + c4*4) = sRed[0][h][c4];
  }
}

// ---------------------------------------------------------------------------
// Kernel G1: split-k partial GEMM. grid (64 rowblocks, 16 ksplits), 384 thr.
// ---------------------------------------------------------------------------
__global__ __launch_bounds__(384) void ipa_outp(
    const float* __restrict__ att, const float* __restrict__ Wout,
    float* __restrict__ ws)
{
  float* partial = ws + OFF_PART;       // [KSPLIT][NRES][Sn]
  const int rb = blockIdx.x;
  const int ks = blockIdx.y;
  const int s  = threadIdx.x;
  const int n0 = rb*OROWS;
  const int j0 = ks*KCHUNK;

  float acc[OROWS];
  #pragma unroll
  for (int r = 0; r < OROWS; ++r) acc[r] = 0.f;

  for (int jg = 0; jg < KCHUNK/4; ++jg) {
    const int j = j0 + jg*4;
    float w0 = Wout[(size_t)(j+0)*Sn + s];
    float w1 = Wout[(size_t)(j+1)*Sn + s];
    float w2 = Wout[(size_t)(j+2)*Sn + s];
    float w3 = Wout[(size_t)(j+3)*Sn + s];
    #pragma unroll
    for (int r = 0; r < OROWS; ++r) {
      float4 av = *reinterpret_cast<const float4*>(att + (size_t)(n0+r)*ATT_COLS + j);
      acc[r] = fmaf(av.x, w0, acc[r]);
      acc[r] = fmaf(av.y, w1, acc[r]);
      acc[r] = fmaf(av.z, w2, acc[r]);
      acc[r] = fmaf(av.w, w3, acc[r]);
    }
  }
  #pragma unroll
  for (int r = 0; r < OROWS; ++r)
    partial[((size_t)ks*NRES + n0 + r)*Sn + s] = acc[r];
}

// ---------------------------------------------------------------------------
// Kernel G2: out[n][s] = b_out[s] + sum_ks partial[ks][n][s].
// ---------------------------------------------------------------------------
__global__ __launch_bounds__(384) void ipa_outred(
    const float* __restrict__ b_out, float* __restrict__ ws,
    float* __restrict__ out)
{
  const float* partial = ws + OFF_PART;
  const int n = blockIdx.x, s = threadIdx.x;
  float a = b_out[s];
  #pragma unroll
  for (int ks = 0; ks < KSPLIT; ++ks)
    a += partial[((size_t)ks*NRES + n)*Sn + s];
  out[(size_t)n*Sn + s] = a;
}

// ---------------------------------------------------------------------------
extern "C" void kernel_launch(void* const* d_in, const int* in_sizes, int n_in,
                              void* d_out, int out_size, void* d_ws, size_t ws_size,
                              hipStream_t stream) {
  const float* single = (const float*)d_in[0];
  const float* pair   = (const float*)d_in[1];
  const float* Rm     = (const float*)d_in[2];
  const float* tr     = (const float*)d_in[3];
  const float* Wq     = (const float*)d_in[4];
  const float* Wk     = (const float*)d_in[5];
  const float* Wv     = (const float*)d_in[6];
  const float* Wqp    = (const float*)d_in[7];
  const float* Wkp    = (const float*)d_in[8];
  const float* Wvp    = (const float*)d_in[9];
  const float* Wb     = (const float*)d_in[10];
  const float* Wout   = (const float*)d_in[11];
  const float* b_out  = (const float*)d_in[12];
  const float* scale_head = (const float*)d_in[13];
  float* ws  = (float*)d_ws;
  float* out = (float*)d_out;

  hipMemsetAsync(ws + OFF_CS, 0, NRES*HH*sizeof(float), stream);
  ipa_proj   <<<dim3(64, 8),  256, 0, stream>>>(single, Rm, tr, Wq, Wk, Wv, Wqp, Wkp, Wvp, ws);
  ipa_pack   <<<dim3(24),     256, 0, stream>>>(scale_head, ws);
  ipa_logits <<<dim3(NRES/NGRP, NRES/256), 256, 0, stream>>>(pair, Wb, ws);
  ipa_softmax<<<dim3(HH*NRES/4), 256, 0, stream>>>(ws);
  ipa_colsum <<<dim3(HH, 8),  256, 0, stream>>>(ws);
  ipa_agg    <<<dim3(HH*NRES/4), 256, 0, stream>>>(Rm, tr, ws);
  ipa_pairagg<<<dim3(NRES),   256, 0, stream>>>(pair, ws);
  ipa_outp   <<<dim3(NRES/OROWS, KSPLIT), 384, 0, stream>>>(ws + OFF_ATT, Wout, ws);
  ipa_outred <<<dim3(NRES),   384, 0, stream>>>(b_out, ws, out);
}